// Round 12
// baseline (145.183 us; speedup 1.0000x reference)
//
#include <hip/hip_runtime.h>
#include <cstdint>
#include <cstddef>

// B=32, S=2048, P=256, N=256, K=8, L=4, M_out=1024
// Factorized: v_k = bf16(W^{8-k}) @ X   (stage 1, fused transpose+stats)
//             c_l = sum_k W_enc[l,k] v_k (streaming combine + finalize)
//             dec[l] = bf16(W^l) @ c_l   (stage 2; W^0 = I exact)
// out = dec + mean*(1-rowsumA) + b_enc*std  (affine fold; rowsums of ROUNDED maps)
// R12 = R11 + race fix: FRAGBUILD(1) reads scr (overlays sB[1]); BSTAGE(1)
// writes sB[1]. R11 had no barrier between them -> gload_lds write-back could
// land in scr before other waves' (or, with compiler hoisting, this wave's)
// ds_reads completed. Fix: lgkmcnt(0)+s_barrier between them.

typedef unsigned short ushort_t;
typedef unsigned int uint_t;
typedef __attribute__((ext_vector_type(8))) short bf16x8;
typedef __attribute__((ext_vector_type(16))) float f32x16;

__device__ __forceinline__ ushort_t f32_to_bf16(float f) {
    uint_t u = __float_as_uint(f);
    u += 0x7FFFu + ((u >> 16) & 1u);   // RNE
    return (ushort_t)(u >> 16);
}
__device__ __forceinline__ float bf16_to_f32(ushort_t h) {
    return __uint_as_float((uint_t)h << 16);
}

// ---------------- W powers: C = A * B, slots 0..6 = W^2..W^8 (idx<0 -> W_base) ----------------
struct PowOps { int sa[4]; int sb[4]; int sd[4]; };

__global__ void powmul(const float* __restrict__ Wb, float* __restrict__ Pw, PowOps ops) {
    __shared__ float As[4 * 256];
    const int mat = blockIdx.x;
    const int r0  = blockIdx.y * 4;
    const int tid = threadIdx.x;
    const float* A  = (ops.sa[mat] < 0) ? Wb : Pw + (size_t)ops.sa[mat] * 65536;
    const float* Bm = (ops.sb[mat] < 0) ? Wb : Pw + (size_t)ops.sb[mat] * 65536;
    float* C        = Pw + (size_t)ops.sd[mat] * 65536;
#pragma unroll
    for (int i = 0; i < 4; ++i) As[i * 256 + tid] = A[(size_t)(r0 + i) * 256 + tid];
    __syncthreads();
    float a0 = 0.f, a1 = 0.f, a2 = 0.f, a3 = 0.f;
    for (int p = 0; p < 256; p += 8) {
        float bv[8];
#pragma unroll
        for (int u = 0; u < 8; ++u) bv[u] = Bm[(size_t)(p + u) * 256 + tid];
#pragma unroll
        for (int u = 0; u < 8; ++u) {
            a0 += As[0 * 256 + p + u] * bv[u];
            a1 += As[1 * 256 + p + u] * bv[u];
            a2 += As[2 * 256 + p + u] * bv[u];
            a3 += As[3 * 256 + p + u] * bv[u];
        }
    }
    C[(size_t)(r0 + 0) * 256 + tid] = a0;
    C[(size_t)(r0 + 1) * 256 + tid] = a1;
    C[(size_t)(r0 + 2) * 256 + tid] = a2;
    C[(size_t)(r0 + 3) * 256 + tid] = a3;
}

// ---------------- prepPb: bf16 powers (Pb[0]=I .. Pb[8]=W^8) + rowsums ----------------
__global__ void prepPb(const float* __restrict__ Pw, const float* __restrict__ Wb,
                       ushort_t* __restrict__ Pb, float* __restrict__ prs) {
    const int ib = blockIdx.x;           // 0..35
    const int e  = ib >> 2;              // exponent 0..8
    const int rq = ib & 3;
    const int tid = threadIdx.x;
    const int q  = rq * 64 + (tid >> 2);
    const int cc = tid & 3;
    uint2* dst = (uint2*)(Pb + (size_t)e * 65536 + q * 256 + cc * 64);
    float s = 0.f;
    if (e == 0) {
#pragma unroll
        for (int i = 0; i < 16; ++i) {
            uint2 o; o.x = 0u; o.y = 0u;
            const int col0 = cc * 64 + i * 4;
            if (q >= col0 && q < col0 + 4) {
                const int j = q - col0;
                if (j == 0) o.x = 0x3F80u; else if (j == 1) o.x = 0x3F800000u;
                else if (j == 2) o.y = 0x3F80u; else o.y = 0x3F800000u;
            }
            dst[i] = o;
        }
        s = 1.0f;
    } else {
        const float* src = (e == 1) ? Wb : (Pw + (size_t)(e - 2) * 65536);
        const float4* sp = (const float4*)(src + (size_t)q * 256 + cc * 64);
#pragma unroll
        for (int i = 0; i < 16; ++i) {
            const float4 v = sp[i];
            const ushort_t h0 = f32_to_bf16(v.x), h1 = f32_to_bf16(v.y);
            const ushort_t h2 = f32_to_bf16(v.z), h3 = f32_to_bf16(v.w);
            s += bf16_to_f32(h0) + bf16_to_f32(h1) + bf16_to_f32(h2) + bf16_to_f32(h3);
            uint2 o; o.x = (uint_t)h0 | ((uint_t)h1 << 16); o.y = (uint_t)h2 | ((uint_t)h3 << 16);
            dst[i] = o;
        }
    }
    s += __shfl_xor(s, 1);
    s += __shfl_xor(s, 2);
    if (cc == 0) prs[e * 256 + q] = s;
}

// ---------------- stage-1 GEMM (fused transpose + stats, hoisted T-phase) ----------------
// vt[k][col][q] = sum_p x[b, 256k+p, n] * Pb[8-k][q][p],  col = b*256+n.
// grid 512 = 64 colT x 8 k (k = bid&7 -> per-XCD Pb locality). 8 waves, 512 thr.
#define GLOAD_LDS16(gsrc, ldst) \
    __builtin_amdgcn_global_load_lds((const __attribute__((address_space(1))) void*)(gsrc), \
                                     (__attribute__((address_space(3))) void*)(ldst), 16, 0, 0)

__global__ __launch_bounds__(512, 4) void gemm_v(
    const ushort_t* __restrict__ Pb, const float* __restrict__ x,
    ushort_t* __restrict__ vt,
    float* __restrict__ psS1, float* __restrict__ psS2)
{
    __shared__ ushort_t sA[4][4096];   // 32 KB: 4 kt-segments [128 col][32 p] macro
    __shared__ ushort_t sB[3][8192];   // 48 KB: Pb tiles [256 q][32 p] macro, 3-deep
    uint_t* scr = (uint_t*)&sB[1][0];  // 16.6 KB overlay (bufs 1-2), stride-65 [p'][np]

    const int bid  = blockIdx.x;
    const int k    = bid & 7;
    const int colT = bid >> 3;             // 0..63
    const int e    = 8 - k;

    const int tid  = threadIdx.x;
    const int lane = tid & 63;
    const int w    = tid >> 6;             // 0..7
    const int wm   = w >> 2;               // 0..1 (col half)
    const int wq   = w & 3;                // 0..3 (q quarter)
    const int li   = lane & 31, lg = lane >> 5;
    const int lq3  = (li >> 1) & 3;
    const int lrow = 2 * (lane >> 3) + ((lane >> 2) & 1);
    const int kc   = (lane & 3) ^ ((lane >> 3) & 3);

    const ushort_t* pbb = Pb + (size_t)e * 65536;
    const int b  = colT >> 1;
    const int n0 = (colT & 1) * 128;
    const float* xseg = x + ((size_t)b * 2048 + k * 256) * 256 + n0;

    const int xp = tid >> 5;               // 0..15
    const int xn = (tid & 31) * 4;         // 0..124

    float4 xr0[4], xr1[4];
    float s1[4] = {0, 0, 0, 0}, s2[4] = {0, 0, 0, 0};

#define BSTAGE(bf_, kt_) do { \
    const int p0_ = (kt_) * 32 + kc * 8; \
    GLOAD_LDS16(pbb + (w * 32 + 0  + lrow) * 256 + p0_, &sB[bf_][(w * 32 + 0)  * 32]); \
    GLOAD_LDS16(pbb + (w * 32 + 16 + lrow) * 256 + p0_, &sB[bf_][(w * 32 + 16) * 32]); \
} while (0)

#define XLOADS(dst_, p0_) do { \
    _Pragma("unroll") \
    for (int i_ = 0; i_ < 4; ++i_) \
        dst_[i_] = *(const float4*)(xseg + (size_t)((p0_) + xp + 16 * i_) * 256 + xn); \
} while (0)

// pack to scr[p'][np], stride 65 (writer 2-way free, FRAG reads conflict-free)
#define SCRW(src_) do { \
    _Pragma("unroll") \
    for (int i_ = 0; i_ < 4; ++i_) { \
        const float4 v_ = src_[i_]; \
        s1[0] += v_.x; s2[0] += v_.x * v_.x; \
        s1[1] += v_.y; s2[1] += v_.y * v_.y; \
        s1[2] += v_.z; s2[2] += v_.z * v_.z; \
        s1[3] += v_.w; s2[3] += v_.w * v_.w; \
        const int pl_ = xp + 16 * i_; \
        scr[pl_ * 65 + (xn >> 1)]     = (uint_t)f32_to_bf16(v_.x) | ((uint_t)f32_to_bf16(v_.y) << 16); \
        scr[pl_ * 65 + (xn >> 1) + 1] = (uint_t)f32_to_bf16(v_.z) | ((uint_t)f32_to_bf16(v_.w) << 16); \
    } \
} while (0)

// scr (64 p' x 64 np) -> sA segments 2s, 2s+1 in macro-row frag layout
#define FRAGBUILD(s_) do { \
    const int R_  = tid >> 2;              /* output col row 0..127 */ \
    const int pc_ = tid & 3; \
    const int np_ = R_ >> 1; \
    const int sh_ = (R_ & 1) * 16; \
    _Pragma("unroll") \
    for (int kh_ = 0; kh_ < 2; ++kh_) { \
        uint_t o_[4]; \
        _Pragma("unroll") \
        for (int u_ = 0; u_ < 4; ++u_) { \
            const int m_ = kh_ * 16 + pc_ * 4 + u_; \
            const uint_t w0_ = scr[(2 * m_) * 65 + np_]; \
            const uint_t w1_ = scr[(2 * m_ + 1) * 65 + np_]; \
            o_[u_] = ((w0_ >> sh_) & 0xFFFFu) | (((w1_ >> sh_) & 0xFFFFu) << 16); \
        } \
        uint4 q_; q_.x = o_[0]; q_.y = o_[1]; q_.z = o_[2]; q_.w = o_[3]; \
        *(uint4*)((char*)&sA[0][0] + (2 * (s_) + kh_) * 8192 + R_ * 64 + ((pc_ ^ ((R_ >> 1) & 3)) << 4)) = q_; \
    } \
} while (0)

    f32x16 acc[2][2];
#pragma unroll
    for (int mm = 0; mm < 2; ++mm)
#pragma unroll
        for (int nn = 0; nn < 2; ++nn)
#pragma unroll
            for (int rr = 0; rr < 16; ++rr) acc[mm][nn][rr] = 0.0f;

#define GKT(i_, kt_, STAGEOP, VM) do { \
    VM; \
    __builtin_amdgcn_s_barrier(); \
    asm volatile("" ::: "memory"); \
    const ushort_t* pa_ = &sA[i_][0]; \
    const ushort_t* px_ = &sB[(i_) % 3][0]; \
    bf16x8 af0, af1, xf0, xf1, ag0, ag1, xg0, xg1; \
    { const int sl_ = lg ^ lq3; \
      const int ro_ = (li >> 1) * 64 + (li & 1) * 32 + sl_ * 8; \
      af0 = *(const bf16x8*)(pa_ + wm * 2048 + ro_); \
      af1 = *(const bf16x8*)(pa_ + wm * 2048 + 1024 + ro_); \
      xf0 = *(const bf16x8*)(px_ + wq * 2048 + ro_); \
      xf1 = *(const bf16x8*)(px_ + wq * 2048 + 1024 + ro_); } \
    { const int sl_ = (2 + lg) ^ lq3; \
      const int ro_ = (li >> 1) * 64 + (li & 1) * 32 + sl_ * 8; \
      ag0 = *(const bf16x8*)(pa_ + wm * 2048 + ro_); \
      ag1 = *(const bf16x8*)(pa_ + wm * 2048 + 1024 + ro_); \
      xg0 = *(const bf16x8*)(px_ + wq * 2048 + ro_); \
      xg1 = *(const bf16x8*)(px_ + wq * 2048 + 1024 + ro_); } \
    STAGEOP; \
    __builtin_amdgcn_s_setprio(1); \
    acc[0][0] = __builtin_amdgcn_mfma_f32_32x32x16_bf16(af0, xf0, acc[0][0], 0, 0, 0); \
    acc[0][1] = __builtin_amdgcn_mfma_f32_32x32x16_bf16(af0, xf1, acc[0][1], 0, 0, 0); \
    acc[1][0] = __builtin_amdgcn_mfma_f32_32x32x16_bf16(af1, xf0, acc[1][0], 0, 0, 0); \
    acc[1][1] = __builtin_amdgcn_mfma_f32_32x32x16_bf16(af1, xf1, acc[1][1], 0, 0, 0); \
    acc[0][0] = __builtin_amdgcn_mfma_f32_32x32x16_bf16(ag0, xg0, acc[0][0], 0, 0, 0); \
    acc[0][1] = __builtin_amdgcn_mfma_f32_32x32x16_bf16(ag0, xg1, acc[0][1], 0, 0, 0); \
    acc[1][0] = __builtin_amdgcn_mfma_f32_32x32x16_bf16(ag1, xg0, acc[1][0], 0, 0, 0); \
    acc[1][1] = __builtin_amdgcn_mfma_f32_32x32x16_bf16(ag1, xg1, acc[1][1], 0, 0, 0); \
    __builtin_amdgcn_s_setprio(0); \
    asm volatile("" ::: "memory"); \
} while (0)

#define VMW(n_) asm volatile("s_waitcnt vmcnt(" #n_ ")" ::: "memory")
#define LGW()   asm volatile("s_waitcnt lgkmcnt(0)" ::: "memory")
#define BARM()  do { __builtin_amdgcn_s_barrier(); asm volatile("" ::: "memory"); } while (0)

#define HALF(h_) do { \
    XLOADS(xr0, (h_) * 128);        /* +4 vm */ \
    XLOADS(xr1, (h_) * 128 + 64);   /* +4 vm */ \
    VMW(4);                          /* xr0 ready (xr1 flying) */ \
    SCRW(xr0); \
    LGW(); \
    BARM(); \
    FRAGBUILD(0); \
    BSTAGE(0, (h_) * 4);             /* sB[0], disjoint from scr: safe */ \
    LGW(); \
    BARM(); \
    VMW(2);                          /* xr1 ready (B0 flying) */ \
    SCRW(xr1); \
    LGW(); \
    BARM(); \
    FRAGBUILD(1); \
    LGW();                           /* RACE FIX: drain scr reads... */ \
    BARM();                          /* ...in ALL waves before sB[1] staging */ \
    BSTAGE(1, (h_) * 4 + 1); \
    GKT(0, (h_) * 4 + 0, BSTAGE(2, (h_) * 4 + 2), VMW(2)); \
    GKT(1, (h_) * 4 + 1, BSTAGE(0, (h_) * 4 + 3), VMW(2)); \
    GKT(2, (h_) * 4 + 2, , VMW(2)); \
    GKT(3, (h_) * 4 + 3, , VMW(0)); \
} while (0)

    HALF(0);
    HALF(1);
#undef HALF
#undef GKT
#undef VMW
#undef LGW
#undef BARM
#undef FRAGBUILD
#undef SCRW
#undef XLOADS
#undef BSTAGE

    // ---- epilogue: vt store (bf16) ----
    ushort_t* vb = vt + (size_t)k * 2097152;
#pragma unroll
    for (int mm = 0; mm < 2; ++mm)
#pragma unroll
        for (int nn = 0; nn < 2; ++nn) {
            const int q = wq * 64 + nn * 32 + li;
#pragma unroll
            for (int rr = 0; rr < 16; ++rr) {
                const int c = colT * 128 + wm * 64 + mm * 32 + ((rr & 3) + 8 * (rr >> 2) + 4 * lg);
                vb[(size_t)c * 256 + q] = f32_to_bf16(acc[mm][nn][rr]);
            }
        }

    // ---- stats reduce across the 16 p-thread-groups (reuse sB[0] as f32) ----
    __syncthreads();
    float* sf = (float*)&sB[0][0];
    *(float4*)(sf + xp * 128 + xn)        = make_float4(s1[0], s1[1], s1[2], s1[3]);
    *(float4*)(sf + 2048 + xp * 128 + xn) = make_float4(s2[0], s2[1], s2[2], s2[3]);
    __syncthreads();
    if (tid < 128) {
        float a = 0.f;
#pragma unroll
        for (int r = 0; r < 16; ++r) a += sf[r * 128 + tid];
        psS1[(size_t)k * 8192 + colT * 128 + tid] = a;
    } else if (tid < 256) {
        const int tt = tid - 128;
        float a = 0.f;
#pragma unroll
        for (int r = 0; r < 16; ++r) a += sf[2048 + r * 128 + tt];
        psS2[(size_t)k * 8192 + colT * 128 + tt] = a;
    }
}

// ---------------- combine: c_l = sum_k we*v_k | finalize mean/std | rsA ----------------
__global__ void combine(const ushort_t* __restrict__ vt, const float* __restrict__ Wenc,
                        ushort_t* __restrict__ c,
                        const float* __restrict__ psS1, const float* __restrict__ psS2,
                        const float* __restrict__ prs, const ushort_t* __restrict__ Pb,
                        float* __restrict__ meanv, float* __restrict__ stdv,
                        float* __restrict__ rsA) {
    __shared__ float uf[256];
    const int bid = blockIdx.x;
    const int t   = threadIdx.x;
    if (bid < 1024) {
        const int col = bid * 8 + (t >> 5);
        const size_t off = (size_t)col * 256 + (t & 31) * 8;
        float a0[8] = {0,0,0,0,0,0,0,0}, a1[8] = {0,0,0,0,0,0,0,0};
        float a2[8] = {0,0,0,0,0,0,0,0}, a3[8] = {0,0,0,0,0,0,0,0};
#pragma unroll
        for (int k = 0; k < 8; ++k) {
            const bf16x8 v = *(const bf16x8*)(vt + (size_t)k * 2097152 + off);
            const float w0 = Wenc[0 * 8 + k], w1 = Wenc[1 * 8 + k];
            const float w2 = Wenc[2 * 8 + k], w3 = Wenc[3 * 8 + k];
#pragma unroll
            for (int j = 0; j < 8; ++j) {
                const float f = bf16_to_f32((ushort_t)v[j]);
                a0[j] += w0 * f; a1[j] += w1 * f; a2[j] += w2 * f; a3[j] += w3 * f;
            }
        }
        bf16x8 o0, o1, o2, o3;
#pragma unroll
        for (int j = 0; j < 8; ++j) {
            o0[j] = (short)f32_to_bf16(a0[j]); o1[j] = (short)f32_to_bf16(a1[j]);
            o2[j] = (short)f32_to_bf16(a2[j]); o3[j] = (short)f32_to_bf16(a3[j]);
        }
        *(bf16x8*)(c + 0 * 2097152 + off) = o0;
        *(bf16x8*)(c + 1 * 2097152 + off) = o1;
        *(bf16x8*)(c + 2 * 2097152 + off) = o2;
        *(bf16x8*)(c + 3 * 2097152 + off) = o3;
    } else if (bid < 1056) {
        const int b = bid - 1024;            // 0..31
        const int col = b * 256 + t;
        float s = 0.f, q = 0.f;
#pragma unroll
        for (int k = 0; k < 8; ++k) {
            s += psS1[(size_t)k * 8192 + col];
            q += psS2[(size_t)k * 8192 + col];
        }
        const float mean = s * (1.0f / 2048.0f);
        float var = q * (1.0f / 2048.0f) - mean * mean;
        var = fmaxf(var, 0.0f);
        meanv[col] = mean;
        stdv [col] = sqrtf(var + 1e-5f);
    } else {
        const int l = bid - 1056;            // 0..3
        float u = 0.f;
#pragma unroll
        for (int k = 0; k < 8; ++k) u += Wenc[l * 8 + k] * prs[(8 - k) * 256 + t];
        uf[t] = u;
        __syncthreads();
        const uint2* rp = (const uint2*)(Pb + (size_t)l * 65536 + t * 256);
        float s = 0.f;
#pragma unroll
        for (int i = 0; i < 64; ++i) {
            const uint2 v = rp[i];
            s += bf16_to_f32((ushort_t)(v.x & 0xffff)) * uf[i * 4 + 0]
               + bf16_to_f32((ushort_t)(v.x >> 16))    * uf[i * 4 + 1]
               + bf16_to_f32((ushort_t)(v.y & 0xffff)) * uf[i * 4 + 2]
               + bf16_to_f32((ushort_t)(v.y >> 16))    * uf[i * 4 + 3];
        }
        rsA[l * 256 + t] = s;
    }
}

// ---------------- stage-2 GEMM: out rows l*256+q' = Pb[l] @ c_l, affine epilogue ----------------
__global__ __launch_bounds__(256, 2) void gemm2(
    const ushort_t* __restrict__ Pb, const ushort_t* __restrict__ c,
    const float* __restrict__ meanv, const float* __restrict__ stdv,
    const float* __restrict__ rsA, const float* __restrict__ benc,
    float* __restrict__ out)
{
    __shared__ ushort_t sAa[3][4096];
    __shared__ ushort_t sBb[3][4096];

    const int bid  = blockIdx.x;             // 0..511
    const int xcd  = bid & 7;
    const int g    = bid >> 3;
    const int colT = xcd + ((g & 7) << 3);   // 0..63
    const int rest = g >> 3;                 // 0..7
    const int l    = rest >> 1;
    const int qpT  = rest & 1;

    const int tid  = threadIdx.x;
    const int lane = tid & 63;
    const int w    = tid >> 6;
    const int wm   = w >> 1, wn = w & 1;
    const int li   = lane & 31, lg = lane >> 5;
    const int lq3  = (li >> 1) & 3;
    const int lrow = 2 * (lane >> 3) + ((lane >> 2) & 1);
    const int kc   = (lane & 3) ^ ((lane >> 3) & 3);

    const ushort_t* ab = Pb + (size_t)l * 65536 + (size_t)(qpT * 128) * 256;
    const ushort_t* cb = c + ((size_t)l * 8192 + colT * 128) * 256;

#define GSTAGE(bf_, kt_) do { \
    const int p0_ = (kt_) * 32 + kc * 8; \
    GLOAD_LDS16(ab + (w * 32 + 0  + lrow) * 256 + p0_, &sAa[bf_][(w * 32 + 0)  * 32]); \
    GLOAD_LDS16(ab + (w * 32 + 16 + lrow) * 256 + p0_, &sAa[bf_][(w * 32 + 16) * 32]); \
    GLOAD_LDS16(cb + (w * 32 + 0  + lrow) * 256 + p0_, &sBb[bf_][(w * 32 + 0)  * 32]); \
    GLOAD_LDS16(cb + (w * 32 + 16 + lrow) * 256 + p0_, &sBb[bf_][(w * 32 + 16) * 32]); \
} while (0)

    f32x16 acc[2][2];
#pragma unroll
    for (int mm = 0; mm < 2; ++mm)
#pragma unroll
        for (int nn = 0; nn < 2; ++nn)
#pragma unroll
            for (int rr = 0; rr < 16; ++rr) acc[mm][nn][rr] = 0.0f;

    GSTAGE(0, 0);
    GSTAGE(1, 1);

#define GKT(kt_) do { \
    if ((kt_) < 7) { asm volatile("s_waitcnt vmcnt(4)" ::: "memory"); } \
    else           { asm volatile("s_waitcnt vmcnt(0)" ::: "memory"); } \
    __builtin_amdgcn_s_barrier(); \
    asm volatile("" ::: "memory"); \
    const ushort_t* pa_ = &sAa[(kt_) % 3][0]; \
    const ushort_t* px_ = &sBb[(kt_) % 3][0]; \
    bf16x8 af[2][2], xf[2][2]; \
    _Pragma("unroll") \
    for (int ks = 0; ks < 2; ++ks) { \
        const int sl = ((ks << 1) + lg) ^ lq3; \
        const int ro = (li >> 1) * 64 + (li & 1) * 32 + sl * 8; \
        af[ks][0] = *(const bf16x8*)(pa_ + wm * 2048 + ro); \
        af[ks][1] = *(const bf16x8*)(pa_ + wm * 2048 + 1024 + ro); \
        xf[ks][0] = *(const bf16x8*)(px_ + wn * 2048 + ro); \
        xf[ks][1] = *(const bf16x8*)(px_ + wn * 2048 + 1024 + ro); \
    } \
    if ((kt_) < 6) { GSTAGE(((kt_) + 2) % 3, (kt_) + 2); } \
    __builtin_amdgcn_s_setprio(1); \
    _Pragma("unroll") \
    for (int ks = 0; ks < 2; ++ks) { \
        acc[0][0] = __builtin_amdgcn_mfma_f32_32x32x16_bf16(af[ks][0], xf[ks][0], acc[0][0], 0, 0, 0); \
        acc[0][1] = __builtin_amdgcn_mfma_f32_32x32x16_bf16(af[ks][0], xf[ks][1], acc[0][1], 0, 0, 0); \
        acc[1][0] = __builtin_amdgcn_mfma_f32_32x32x16_bf16(af[ks][1], xf[ks][0], acc[1][0], 0, 0, 0); \
        acc[1][1] = __builtin_amdgcn_mfma_f32_32x32x16_bf16(af[ks][1], xf[ks][1], acc[1][1], 0, 0, 0); \
    } \
    __builtin_amdgcn_s_setprio(0); \
    asm volatile("" ::: "memory"); \
} while (0)

    GKT(0); GKT(1); GKT(2); GKT(3); GKT(4); GKT(5); GKT(6); GKT(7);
#undef GKT
#undef GSTAGE

    const float be = benc[l];
    float mn[2], sd[2];
#pragma unroll
    for (int nn = 0; nn < 2; ++nn) {
        const int col = colT * 128 + wn * 64 + nn * 32 + li;
        mn[nn] = meanv[col];
        sd[nn] = stdv [col];
    }
#pragma unroll
    for (int mm = 0; mm < 2; ++mm)
#pragma unroll
        for (int nn = 0; nn < 2; ++nn) {
            const int col = colT * 128 + wn * 64 + nn * 32 + li;
            const int bq = col >> 8, nq = col & 255;
            const float ben = be * sd[nn];
#pragma unroll
            for (int rr = 0; rr < 16; ++rr) {
                const int trow = l * 256 + qpT * 128 + wm * 64 + mm * 32
                               + ((rr & 3) + 8 * (rr >> 2) + 4 * lg);
                out[((size_t)bq * 1024 + trow) * 256 + nq] =
                    acc[mm][nn][rr] + mn[nn] * (1.0f - rsA[trow]) + ben;
            }
        }
}

// ---------------- launch ----------------
extern "C" void kernel_launch(void* const* d_in, const int* in_sizes, int n_in,
                              void* d_out, int out_size, void* d_ws, size_t ws_size,
                              hipStream_t stream) {
    (void)in_sizes; (void)n_in; (void)out_size; (void)ws_size;
    const float* x_enc  = (const float*)d_in[0];
    const float* W_base = (const float*)d_in[4];
    const float* W_enc  = (const float*)d_in[5];
    const float* b_enc  = (const float*)d_in[6];
    float* out = (float*)d_out;

    char* ws = (char*)d_ws;
    float*    wsP    = (float*)(ws);                  // 7*65536 f32 (W^2..W^8)
    ushort_t* wsPb   = (ushort_t*)(ws + 0x200000);    // 9*65536 bf16 (I..W^8)
    float*    wsPrs  = (float*)(ws + 0x340000);       // 9*256 f32
    float*    wsS1   = (float*)(ws + 0x350000);       // 8*8192 f32 (256KB)
    float*    wsS2   = (float*)(ws + 0x390000);       // 256KB
    float*    wsMean = (float*)(ws + 0x3D0000);       // 8192 f32
    float*    wsStd  = (float*)(ws + 0x3E0000);
    float*    wsRsA  = (float*)(ws + 0x3F0000);       // 1024 f32
    ushort_t* wsVt   = (ushort_t*)(ws + 0x400000);    // [8][8192][256] bf16 (32 MB)
    ushort_t* wsC    = (ushort_t*)(ws + 0x2400000);   // [4][8192][256] bf16 (16 MB)

    // powers: slots 0..6 = W^2..W^8 (idx<0 = W_base)
    { PowOps o{{-1, 0, 0, 0}, {-1, 0, 0, 0}, {0, 0, 0, 0}};          // W2
      powmul<<<dim3(1, 64), 256, 0, stream>>>(W_base, wsP, o); }
    { PowOps o{{0, 0, 0, 0}, {-1, 0, 0, 0}, {1, 2, 0, 0}};           // W3, W4
      powmul<<<dim3(2, 64), 256, 0, stream>>>(W_base, wsP, o); }
    { PowOps o{{2, 2, 2, 2}, {-1, 0, 1, 2}, {3, 4, 5, 6}};           // W5..W8
      powmul<<<dim3(4, 64), 256, 0, stream>>>(W_base, wsP, o); }

    prepPb<<<36, 256, 0, stream>>>(wsP, W_base, wsPb, wsPrs);

    gemm_v<<<512, 512, 0, stream>>>(wsPb, x_enc, wsVt, wsS1, wsS2);

    combine<<<1060, 256, 0, stream>>>(wsVt, W_enc, wsC, wsS1, wsS2, wsPrs, wsPb,
                                      wsMean, wsStd, wsRsA);

    gemm2<<<512, 256, 0, stream>>>(wsPb, wsC, wsMean, wsStd, wsRsA, b_enc, out);
}

// Round 13
// 99.640 us; speedup vs baseline: 1.4571x; 1.4571x over previous
//
#include <hip/hip_runtime.h>
#include <cstdint>
#include <cstddef>

// B=32, S=2048, P=256, N=256, K=8, L=4, M_out=1024
// Factorized: v_k = bf16(W^{8-k}) @ X   (stage 1, reads transposed Xt)
//             c_l = sum_k W_enc[l,k] v_k (streaming combine + finalize)
//             dec[l] = bf16(W^l) @ c_l   (stage 2; W^0 = I exact)
// out = dec + mean*(1-rowsumA) + b_enc*std  (affine fold; rowsums of ROUNDED maps)
// R13 = revert to proven R8 pipeline (fused-transpose r9-r12 was register-starved:
// 64 arch VGPRs left after acc AGPRs -> ~120MB scratch spill traffic).
// Only deletion-grade changes vs R8: prepPb fused into powmul (convert+rowsum
// in-register on the rows each block already holds), prep = pure transpose.

typedef unsigned short ushort_t;
typedef unsigned int uint_t;
typedef __attribute__((ext_vector_type(8))) short bf16x8;
typedef __attribute__((ext_vector_type(16))) float f32x16;

__device__ __forceinline__ ushort_t f32_to_bf16(float f) {
    uint_t u = __float_as_uint(f);
    u += 0x7FFFu + ((u >> 16) & 1u);   // RNE
    return (ushort_t)(u >> 16);
}
__device__ __forceinline__ float bf16_to_f32(ushort_t h) {
    return __uint_as_float((uint_t)h << 16);
}

// ---------------- powers + bf16 convert + rowsums, fused ----------------
// Pb[e] = bf16(W^e), e=0..8 (Pb[0]=I). prs[e][q] = rowsum(Pb[e]).
// sa >= 0: f32 slot (0=W2,1=W3,2=W4); -1: W_base; -2: identity; -3: copy W_base.
// sd >= 0: also store f32 result to Pw slot sd (needed only for W2,W3,W4).
struct PowOps { int sa[4]; int sb[4]; int sd[4]; int ed[4]; };

__global__ void powmulc(const float* __restrict__ Wb, float* __restrict__ Pw,
                        ushort_t* __restrict__ Pb, float* __restrict__ prs, PowOps ops) {
    __shared__ float As[4 * 256];
    __shared__ float red[4][4];
    const int mat = blockIdx.x;
    const int r0  = blockIdx.y * 4;
    const int tid = threadIdx.x;
    const int e   = ops.ed[mat];
    const int sa  = ops.sa[mat];
    float a[4];
    if (sa == -2) {
#pragma unroll
        for (int i = 0; i < 4; ++i) a[i] = (r0 + i == tid) ? 1.0f : 0.0f;
    } else if (sa == -3) {
#pragma unroll
        for (int i = 0; i < 4; ++i) a[i] = Wb[(size_t)(r0 + i) * 256 + tid];
    } else {
        const float* A  = (sa < 0) ? Wb : Pw + (size_t)sa * 65536;
        const float* Bm = (ops.sb[mat] < 0) ? Wb : Pw + (size_t)ops.sb[mat] * 65536;
#pragma unroll
        for (int i = 0; i < 4; ++i) As[i * 256 + tid] = A[(size_t)(r0 + i) * 256 + tid];
        __syncthreads();
        float a0 = 0.f, a1 = 0.f, a2 = 0.f, a3 = 0.f;
        for (int p = 0; p < 256; p += 8) {
            float bv[8];
#pragma unroll
            for (int u = 0; u < 8; ++u) bv[u] = Bm[(size_t)(p + u) * 256 + tid];
#pragma unroll
            for (int u = 0; u < 8; ++u) {
                a0 += As[0 * 256 + p + u] * bv[u];
                a1 += As[1 * 256 + p + u] * bv[u];
                a2 += As[2 * 256 + p + u] * bv[u];
                a3 += As[3 * 256 + p + u] * bv[u];
            }
        }
        a[0] = a0; a[1] = a1; a[2] = a2; a[3] = a3;
        if (ops.sd[mat] >= 0) {
            float* C = Pw + (size_t)ops.sd[mat] * 65536;
#pragma unroll
            for (int i = 0; i < 4; ++i) C[(size_t)(r0 + i) * 256 + tid] = a[i];
        }
        __syncthreads();   // As reuse barrier (red is separate, but keep clean)
    }
    // convert + bf16 store + rowsums of the ROUNDED rows
    const int lane = tid & 63, wv = tid >> 6;
    float rs[4];
#pragma unroll
    for (int i = 0; i < 4; ++i) {
        const ushort_t h = f32_to_bf16(a[i]);
        Pb[(size_t)e * 65536 + (size_t)(r0 + i) * 256 + tid] = h;
        float v = bf16_to_f32(h);
        v += __shfl_xor(v, 1);  v += __shfl_xor(v, 2);  v += __shfl_xor(v, 4);
        v += __shfl_xor(v, 8);  v += __shfl_xor(v, 16); v += __shfl_xor(v, 32);
        rs[i] = v;
    }
    if (lane == 0) {
#pragma unroll
        for (int i = 0; i < 4; ++i) red[i][wv] = rs[i];
    }
    __syncthreads();
    if (tid < 4) prs[e * 256 + r0 + tid] = red[tid][0] + red[tid][1] + red[tid][2] + red[tid][3];
}

// ---------------- prep: transpose RAW x + bf16 convert + stats partials ----------------
__global__ void prep(const float* __restrict__ x, ushort_t* __restrict__ Xt,
                     float* __restrict__ ps1, float* __restrict__ ps2) {
    __shared__ float lds[64 * 65];
    __shared__ float red1[16 * 64];
    __shared__ float red2[16 * 64];
    const int bid = blockIdx.x;
    const int st = bid & 31;
    const int nt = (bid >> 5) & 3;
    const int b  = bid >> 7;
    const int tid = threadIdx.x;
    const int c = tid & 15, r = tid >> 4;
    const int s0 = st * 64;
    float s1[4] = {0,0,0,0}, s2[4] = {0,0,0,0};
#pragma unroll
    for (int it = 0; it < 4; ++it) {
        const int ii = r + it * 16;
        const float4 v = *(const float4*)(x + ((size_t)b * 2048 + s0 + ii) * 256 + nt * 64 + c * 4);
        const float vv[4] = {v.x, v.y, v.z, v.w};
#pragma unroll
        for (int jj = 0; jj < 4; ++jj) {
            lds[ii * 65 + c * 4 + jj] = vv[jj];
            s1[jj] += vv[jj]; s2[jj] += vv[jj] * vv[jj];
        }
    }
#pragma unroll
    for (int jj = 0; jj < 4; ++jj) { red1[r * 64 + c * 4 + jj] = s1[jj]; red2[r * 64 + c * 4 + jj] = s2[jj]; }
    __syncthreads();
    if (tid < 64) {
        float a = 0.f, q = 0.f;
#pragma unroll
        for (int rr = 0; rr < 16; ++rr) { a += red1[rr * 64 + tid]; q += red2[rr * 64 + tid]; }
        const size_t o = (size_t)st * 8192 + b * 256 + nt * 64 + tid;
        ps1[o] = a; ps2[o] = q;
    }
#pragma unroll
    for (int step = 0; step < 8; ++step) {
        const int npr = step * 8 + (tid >> 5);
        const int sp  = (tid & 31) * 2;
        const float f0 = lds[sp * 65 + npr];
        const float f1 = lds[(sp + 1) * 65 + npr];
        const uint_t packed = (uint_t)f32_to_bf16(f0) | ((uint_t)f32_to_bf16(f1) << 16);
        *(uint_t*)(Xt + ((size_t)b * 256 + nt * 64 + npr) * 2048 + s0 + sp) = packed;
    }
}

// ---------------- stage-1 GEMM: vt[k][col][q] = (Xt_colslice @ Pb[8-k]^T) ----------------
#define GLOAD_LDS16(gsrc, ldst) \
    __builtin_amdgcn_global_load_lds((const __attribute__((address_space(1))) void*)(gsrc), \
                                     (__attribute__((address_space(3))) void*)(ldst), 16, 0, 0)

__global__ __launch_bounds__(256, 2) void gemm_v(
    const ushort_t* __restrict__ Pb,     // 9*65536 bf16 (e=0..8)
    const ushort_t* __restrict__ Xt,     // [8192][2048] bf16
    ushort_t* __restrict__ vt)           // [8][8192][256] bf16
{
    __shared__ ushort_t sAa[3][4096];    // A = Xt tile [128 rows x 32k] x3 (24 KB)
    __shared__ ushort_t sBb[3][8192];    // B = power tile [256 rows x 32k] x3 (48 KB)

    const int bid = blockIdx.x;
    const int tid = threadIdx.x;

    // grid 512 = 8 xcd x 8 colT-group x 8 k
    const int xcd  = bid & 7;
    const int g    = bid >> 3;
    const int colT = xcd + ((g & 7) << 3);   // 0..63 (128 Xt rows each)
    const int k    = g >> 3;                 // 0..7
    const int e    = 8 - k;

    const int lane = tid & 63;
    const int w    = tid >> 6;               // 0..3
    const int wm   = w >> 1, wn = w & 1;
    const int li   = lane & 31, lg = lane >> 5;
    const int lq3  = (li >> 1) & 3;
    const int lrow = 2 * (lane >> 3) + ((lane >> 2) & 1);
    const int kc   = (lane & 3) ^ ((lane >> 3) & 3);

    const ushort_t* xtb = Xt + (size_t)(colT * 128) * 2048 + k * 256;  // + row*2048 + p
    const ushort_t* pbb = Pb + (size_t)e * 65536;                      // + q*256 + p

#define VSTAGE(bf_, kt_) do { \
    const int p0_ = (kt_) * 32 + kc * 8; \
    GLOAD_LDS16(xtb + (size_t)(w * 32 + 0  + lrow) * 2048 + p0_, &sAa[bf_][(w * 32 + 0)  * 32]); \
    GLOAD_LDS16(xtb + (size_t)(w * 32 + 16 + lrow) * 2048 + p0_, &sAa[bf_][(w * 32 + 16) * 32]); \
    GLOAD_LDS16(pbb + (w * 64 + 0  + lrow) * 256 + p0_, &sBb[bf_][(w * 64 + 0)  * 32]); \
    GLOAD_LDS16(pbb + (w * 64 + 16 + lrow) * 256 + p0_, &sBb[bf_][(w * 64 + 16) * 32]); \
    GLOAD_LDS16(pbb + (w * 64 + 32 + lrow) * 256 + p0_, &sBb[bf_][(w * 64 + 32) * 32]); \
    GLOAD_LDS16(pbb + (w * 64 + 48 + lrow) * 256 + p0_, &sBb[bf_][(w * 64 + 48) * 32]); \
} while (0)

    f32x16 acc[2][4];
#pragma unroll
    for (int mm = 0; mm < 2; ++mm)
#pragma unroll
        for (int nn = 0; nn < 4; ++nn)
#pragma unroll
            for (int rr = 0; rr < 16; ++rr) acc[mm][nn][rr] = 0.0f;

    VSTAGE(0, 0);
    VSTAGE(1, 1);

#define VKT(kt_) do { \
    if ((kt_) < 7) { asm volatile("s_waitcnt vmcnt(6)" ::: "memory"); } \
    else           { asm volatile("s_waitcnt vmcnt(0)" ::: "memory"); } \
    __builtin_amdgcn_s_barrier(); \
    asm volatile("" ::: "memory"); \
    const ushort_t* pa_ = &sAa[(kt_) % 3][0]; \
    const ushort_t* px_ = &sBb[(kt_) % 3][0]; \
    bf16x8 af[2][2], xf[2][4]; \
    _Pragma("unroll") \
    for (int ks = 0; ks < 2; ++ks) { \
        const int sl = ((ks << 1) + lg) ^ lq3; \
        const int ro = (li >> 1) * 64 + (li & 1) * 32 + sl * 8; \
        af[ks][0] = *(const bf16x8*)(pa_ + wm * 2048 + ro); \
        af[ks][1] = *(const bf16x8*)(pa_ + wm * 2048 + 1024 + ro); \
        xf[ks][0] = *(const bf16x8*)(px_ + wn * 4096 + ro); \
        xf[ks][1] = *(const bf16x8*)(px_ + wn * 4096 + 1024 + ro); \
        xf[ks][2] = *(const bf16x8*)(px_ + wn * 4096 + 2048 + ro); \
        xf[ks][3] = *(const bf16x8*)(px_ + wn * 4096 + 3072 + ro); \
    } \
    if ((kt_) < 6) { VSTAGE(((kt_) + 2) % 3, (kt_) + 2); } \
    __builtin_amdgcn_s_setprio(1); \
    _Pragma("unroll") \
    for (int ks = 0; ks < 2; ++ks) \
        _Pragma("unroll") \
        for (int mm = 0; mm < 2; ++mm) \
            _Pragma("unroll") \
            for (int nn = 0; nn < 4; ++nn) \
                acc[mm][nn] = __builtin_amdgcn_mfma_f32_32x32x16_bf16(af[ks][mm], xf[ks][nn], acc[mm][nn], 0, 0, 0); \
    __builtin_amdgcn_s_setprio(0); \
    asm volatile("" ::: "memory"); \
} while (0)

    VKT(0); VKT(1); VKT(2); VKT(3); VKT(4); VKT(5); VKT(6); VKT(7);
#undef VKT
#undef VSTAGE

    // epilogue: vt[k][col][q] bf16 (lane li = q -> contiguous 64B stores)
    ushort_t* vb = vt + (size_t)k * 2097152;
#pragma unroll
    for (int mm = 0; mm < 2; ++mm)
#pragma unroll
        for (int nn = 0; nn < 4; ++nn) {
            const int q = wn * 128 + nn * 32 + li;
#pragma unroll
            for (int rr = 0; rr < 16; ++rr) {
                const int c = colT * 128 + wm * 64 + mm * 32 + ((rr & 3) + 8 * (rr >> 2) + 4 * lg);
                vb[(size_t)c * 256 + q] = f32_to_bf16(acc[mm][nn][rr]);
            }
        }
}

// ---------------- combine: c_l = sum_k we*v_k | finalize mean/std | rsA ----------------
__global__ void combine(const ushort_t* __restrict__ vt, const float* __restrict__ Wenc,
                        ushort_t* __restrict__ c,
                        const float* __restrict__ ps1, const float* __restrict__ ps2,
                        const float* __restrict__ prs, const ushort_t* __restrict__ Pb,
                        float* __restrict__ meanv, float* __restrict__ stdv,
                        float* __restrict__ rsA) {
    __shared__ float uf[256];
    const int bid = blockIdx.x;
    const int t   = threadIdx.x;
    if (bid < 1024) {
        const int col = bid * 8 + (t >> 5);
        const size_t off = (size_t)col * 256 + (t & 31) * 8;
        float a0[8] = {0,0,0,0,0,0,0,0}, a1[8] = {0,0,0,0,0,0,0,0};
        float a2[8] = {0,0,0,0,0,0,0,0}, a3[8] = {0,0,0,0,0,0,0,0};
#pragma unroll
        for (int k = 0; k < 8; ++k) {
            const bf16x8 v = *(const bf16x8*)(vt + (size_t)k * 2097152 + off);
            const float w0 = Wenc[0 * 8 + k], w1 = Wenc[1 * 8 + k];
            const float w2 = Wenc[2 * 8 + k], w3 = Wenc[3 * 8 + k];
#pragma unroll
            for (int j = 0; j < 8; ++j) {
                const float f = bf16_to_f32((ushort_t)v[j]);
                a0[j] += w0 * f; a1[j] += w1 * f; a2[j] += w2 * f; a3[j] += w3 * f;
            }
        }
        bf16x8 o0, o1, o2, o3;
#pragma unroll
        for (int j = 0; j < 8; ++j) {
            o0[j] = (short)f32_to_bf16(a0[j]); o1[j] = (short)f32_to_bf16(a1[j]);
            o2[j] = (short)f32_to_bf16(a2[j]); o3[j] = (short)f32_to_bf16(a3[j]);
        }
        *(bf16x8*)(c + 0 * 2097152 + off) = o0;
        *(bf16x8*)(c + 1 * 2097152 + off) = o1;
        *(bf16x8*)(c + 2 * 2097152 + off) = o2;
        *(bf16x8*)(c + 3 * 2097152 + off) = o3;
    } else if (bid < 1056) {
        const int b = bid - 1024;            // 0..31
        float s = 0.f, q = 0.f;
#pragma unroll
        for (int st = 0; st < 32; ++st) {
            s += ps1[(size_t)st * 8192 + b * 256 + t];
            q += ps2[(size_t)st * 8192 + b * 256 + t];
        }
        const float mean = s * (1.0f / 2048.0f);
        float var = q * (1.0f / 2048.0f) - mean * mean;
        var = fmaxf(var, 0.0f);
        meanv[b * 256 + t] = mean;
        stdv [b * 256 + t] = sqrtf(var + 1e-5f);
    } else {
        const int l = bid - 1056;            // 0..3
        float u = 0.f;
#pragma unroll
        for (int k = 0; k < 8; ++k) u += Wenc[l * 8 + k] * prs[(8 - k) * 256 + t];
        uf[t] = u;
        __syncthreads();
        const uint2* rp = (const uint2*)(Pb + (size_t)l * 65536 + t * 256);
        float s = 0.f;
#pragma unroll
        for (int i = 0; i < 64; ++i) {
            const uint2 v = rp[i];
            s += bf16_to_f32((ushort_t)(v.x & 0xffff)) * uf[i * 4 + 0]
               + bf16_to_f32((ushort_t)(v.x >> 16))    * uf[i * 4 + 1]
               + bf16_to_f32((ushort_t)(v.y & 0xffff)) * uf[i * 4 + 2]
               + bf16_to_f32((ushort_t)(v.y >> 16))    * uf[i * 4 + 3];
        }
        rsA[l * 256 + t] = s;
    }
}

// ---------------- stage-2 GEMM: out rows l*256+q' = Pb[l] @ c_l, affine epilogue ----------------
__global__ __launch_bounds__(256, 2) void gemm2(
    const ushort_t* __restrict__ Pb, const ushort_t* __restrict__ c,
    const float* __restrict__ meanv, const float* __restrict__ stdv,
    const float* __restrict__ rsA, const float* __restrict__ benc,
    float* __restrict__ out)
{
    __shared__ ushort_t sAa[3][4096];
    __shared__ ushort_t sBb[3][4096];

    const int bid  = blockIdx.x;             // 0..511
    const int xcd  = bid & 7;
    const int g    = bid >> 3;
    const int colT = xcd + ((g & 7) << 3);   // 0..63
    const int rest = g >> 3;                 // 0..7
    const int l    = rest >> 1;
    const int qpT  = rest & 1;

    const int tid  = threadIdx.x;
    const int lane = tid & 63;
    const int w    = tid >> 6;
    const int wm   = w >> 1, wn = w & 1;
    const int li   = lane & 31, lg = lane >> 5;
    const int lq3  = (li >> 1) & 3;
    const int lrow = 2 * (lane >> 3) + ((lane >> 2) & 1);
    const int kc   = (lane & 3) ^ ((lane >> 3) & 3);

    const ushort_t* ab = Pb + (size_t)l * 65536 + (size_t)(qpT * 128) * 256;
    const ushort_t* cb = c + ((size_t)l * 8192 + colT * 128) * 256;

#define GSTAGE(bf_, kt_) do { \
    const int p0_ = (kt_) * 32 + kc * 8; \
    GLOAD_LDS16(ab + (w * 32 + 0  + lrow) * 256 + p0_, &sAa[bf_][(w * 32 + 0)  * 32]); \
    GLOAD_LDS16(ab + (w * 32 + 16 + lrow) * 256 + p0_, &sAa[bf_][(w * 32 + 16) * 32]); \
    GLOAD_LDS16(cb + (w * 32 + 0  + lrow) * 256 + p0_, &sBb[bf_][(w * 32 + 0)  * 32]); \
    GLOAD_LDS16(cb + (w * 32 + 16 + lrow) * 256 + p0_, &sBb[bf_][(w * 32 + 16) * 32]); \
} while (0)

    f32x16 acc[2][2];
#pragma unroll
    for (int mm = 0; mm < 2; ++mm)
#pragma unroll
        for (int nn = 0; nn < 2; ++nn)
#pragma unroll
            for (int rr = 0; rr < 16; ++rr) acc[mm][nn][rr] = 0.0f;

    GSTAGE(0, 0);
    GSTAGE(1, 1);

#define GKT(kt_) do { \
    if ((kt_) < 7) { asm volatile("s_waitcnt vmcnt(4)" ::: "memory"); } \
    else           { asm volatile("s_waitcnt vmcnt(0)" ::: "memory"); } \
    __builtin_amdgcn_s_barrier(); \
    asm volatile("" ::: "memory"); \
    const ushort_t* pa_ = &sAa[(kt_) % 3][0]; \
    const ushort_t* px_ = &sBb[(kt_) % 3][0]; \
    bf16x8 af[2][2], xf[2][2]; \
    _Pragma("unroll") \
    for (int ks = 0; ks < 2; ++ks) { \
        const int sl = ((ks << 1) + lg) ^ lq3; \
        const int ro = (li >> 1) * 64 + (li & 1) * 32 + sl * 8; \
        af[ks][0] = *(const bf16x8*)(pa_ + wm * 2048 + ro); \
        af[ks][1] = *(const bf16x8*)(pa_ + wm * 2048 + 1024 + ro); \
        xf[ks][0] = *(const bf16x8*)(px_ + wn * 2048 + ro); \
        xf[ks][1] = *(const bf16x8*)(px_ + wn * 2048 + 1024 + ro); \
    } \
    if ((kt_) < 6) { GSTAGE(((kt_) + 2) % 3, (kt_) + 2); } \
    __builtin_amdgcn_s_setprio(1); \
    _Pragma("unroll") \
    for (int ks = 0; ks < 2; ++ks) { \
        acc[0][0] = __builtin_amdgcn_mfma_f32_32x32x16_bf16(af[ks][0], xf[ks][0], acc[0][0], 0, 0, 0); \
        acc[0][1] = __builtin_amdgcn_mfma_f32_32x32x16_bf16(af[ks][0], xf[ks][1], acc[0][1], 0, 0, 0); \
        acc[1][0] = __builtin_amdgcn_mfma_f32_32x32x16_bf16(af[ks][1], xf[ks][0], acc[1][0], 0, 0, 0); \
        acc[1][1] = __builtin_amdgcn_mfma_f32_32x32x16_bf16(af[ks][1], xf[ks][1], acc[1][1], 0, 0, 0); \
    } \
    __builtin_amdgcn_s_setprio(0); \
    asm volatile("" ::: "memory"); \
} while (0)

    GKT(0); GKT(1); GKT(2); GKT(3); GKT(4); GKT(5); GKT(6); GKT(7);
#undef GKT
#undef GSTAGE

    const float be = benc[l];
    float mn[2], sd[2];
#pragma unroll
    for (int nn = 0; nn < 2; ++nn) {
        const int col = colT * 128 + wn * 64 + nn * 32 + li;
        mn[nn] = meanv[col];
        sd[nn] = stdv [col];
    }
#pragma unroll
    for (int mm = 0; mm < 2; ++mm)
#pragma unroll
        for (int nn = 0; nn < 2; ++nn) {
            const int col = colT * 128 + wn * 64 + nn * 32 + li;
            const int bq = col >> 8, nq = col & 255;
            const float ben = be * sd[nn];
#pragma unroll
            for (int rr = 0; rr < 16; ++rr) {
                const int trow = l * 256 + qpT * 128 + wm * 64 + mm * 32
                               + ((rr & 3) + 8 * (rr >> 2) + 4 * lg);
                out[((size_t)bq * 1024 + trow) * 256 + nq] =
                    acc[mm][nn][rr] + mn[nn] * (1.0f - rsA[trow]) + ben;
            }
        }
}

// ---------------- launch ----------------
extern "C" void kernel_launch(void* const* d_in, const int* in_sizes, int n_in,
                              void* d_out, int out_size, void* d_ws, size_t ws_size,
                              hipStream_t stream) {
    (void)in_sizes; (void)n_in; (void)out_size; (void)ws_size;
    const float* x_enc  = (const float*)d_in[0];
    const float* W_base = (const float*)d_in[4];
    const float* W_enc  = (const float*)d_in[5];
    const float* b_enc  = (const float*)d_in[6];
    float* out = (float*)d_out;

    char* ws = (char*)d_ws;
    float*    wsP    = (float*)(ws);                  // 3*65536 f32 (W2,W3,W4)
    ushort_t* wsPb   = (ushort_t*)(ws + 0x200000);    // 9*65536 bf16 (I..W^8)
    float*    wsPrs  = (float*)(ws + 0x340000);       // 9*256 f32
    float*    wsS1   = (float*)(ws + 0x350000);       // 32*8192 f32 (1 MB)
    float*    wsS2   = (float*)(ws + 0x450000);       // 1 MB
    float*    wsMean = (float*)(ws + 0x550000);       // 8192 f32
    float*    wsStd  = (float*)(ws + 0x560000);
    float*    wsRsA  = (float*)(ws + 0x570000);       // 1024 f32
    ushort_t* wsXt   = (ushort_t*)(ws + 0x600000);    // [8192][2048] bf16 (32 MB)
    ushort_t* wsC    = (ushort_t*)(ws + 0x600000);    // c aliases Xt (dead after gemm_v)
    ushort_t* wsVt   = (ushort_t*)(ws + 0x2600000);   // [8][8192][256] bf16 (32 MB)

    // L1: W2 (f32 slot0 + Pb[2]) | copy W -> Pb[1] | identity -> Pb[0]
    { PowOps o{{-1, -3, -2, 0}, {-1, 0, 0, 0}, {0, -1, -1, 0}, {2, 1, 0, 0}};
      powmulc<<<dim3(3, 64), 256, 0, stream>>>(W_base, wsP, wsPb, wsPrs, o); }
    // L2: W3 = W2*W (slot1, Pb[3]) | W4 = W2*W2 (slot2, Pb[4])
    { PowOps o{{0, 0, 0, 0}, {-1, 0, 0, 0}, {1, 2, 0, 0}, {3, 4, 0, 0}};
      powmulc<<<dim3(2, 64), 256, 0, stream>>>(W_base, wsP, wsPb, wsPrs, o); }
    // L3: W5..W8 = W4*{W,W2,W3,W4} (bf16 only -> Pb[5..8])
    { PowOps o{{2, 2, 2, 2}, {-1, 0, 1, 2}, {-1, -1, -1, -1}, {5, 6, 7, 8}};
      powmulc<<<dim3(4, 64), 256, 0, stream>>>(W_base, wsP, wsPb, wsPrs, o); }

    prep<<<4096, 256, 0, stream>>>(x_enc, wsXt, wsS1, wsS2);

    gemm_v<<<512, 256, 0, stream>>>(wsPb, wsXt, wsVt);

    combine<<<1060, 256, 0, stream>>>(wsVt, W_enc, wsC, wsS1, wsS2, wsPrs, wsPb,
                                      wsMean, wsStd, wsRsA);

    gemm2<<<512, 256, 0, stream>>>(wsPb, wsC, wsMean, wsStd, wsRsA, b_enc, out);
}